// Round 7
// baseline (165.172 us; speedup 1.0000x reference)
//
#include <hip/hip_runtime.h>
#include <hip/hip_bf16.h>

#define BB 8
#define CC 256
#define NN 4096
#define LOG2E 1.44269504088896340736f
#define SHIFT 48.0f

typedef __attribute__((ext_vector_type(8))) short short8;
typedef __attribute__((ext_vector_type(4))) float f32x4;

static __device__ __forceinline__ unsigned short f2b(float x) {
  __hip_bfloat16 h = __float2bfloat16(x);   // RNE
  return *reinterpret_cast<unsigned short*>(&h);
}
static __device__ __forceinline__ unsigned int pk2(float a, float b) {
  return (unsigned int)f2b(a) | ((unsigned int)f2b(b) << 16);
}

// ---------------------------------------------------------------------------
// ws layout (bytes):
//   cshift @ 131072 : [B][N] f32  c[k] = SHIFT + log2(sum exp2(S-SHIFT))
//   wA   @ 262144   : [20 mg][8 kg][64 l][8 e] bf16 W A-frags    163840
//   ball @ 425984   : [320] f32 biases (f rows pre-scaled LOG2E)   1280
//   fA   @ 427520   : [B][256 kg][64 l][8 e] bf16 (f^T*LOG2E)   2097152
//   gB   @ 2524672  : [B][256 ig][64 l][8 e] bf16               2097152
//   hA   @ 4621824  : [B][16 cg][128 kc][64 l][8 e] bf16       16777216
// Frag conventions (mfma_f32_16x16x32_bf16, m89/m91-verified):
//   A[m][k]: lane l holds m=l&15, k=(l>>4)*8+e   (B[k][n] identical bit layout)
//   D[m][n]: lane l reg r holds m=(l>>4)*4+r, n=l&15
// P = exp2(S - c[k]) with c >= rowmax  ->  P in [0,1], no inf/NaN possible.
// ---------------------------------------------------------------------------

// Kernel 0: W -> A-frags (bf16), LOG2E folded into f rows; biases -> ball.
__global__ __launch_bounds__(256) void k_wprep(
    const float* __restrict__ Wf, const float* __restrict__ bfv,
    const float* __restrict__ Wg, const float* __restrict__ bgv,
    const float* __restrict__ Wh, const float* __restrict__ bhv,
    unsigned short* __restrict__ wA, float* __restrict__ ball)
{
  const int t = threadIdx.x;
  const int fi = blockIdx.x * 4 + (t >> 6);   // frag index 0..159 (mg*8+kg)
  const int l = t & 63;
  const int mg = fi >> 3, kg = fi & 7;
  const int o = mg * 16 + (l & 15);
  const int c0 = kg * 32 + (l >> 4) * 8;
  const float* src; float scale = 1.0f;
  if (o < 32)      { src = Wf + (size_t)o * CC; scale = LOG2E; }
  else if (o < 64) { src = Wg + (size_t)(o - 32) * CC; }
  else             { src = Wh + (size_t)(o - 64) * CC; }
  float4 a = *(const float4*)(src + c0);
  float4 c = *(const float4*)(src + c0 + 4);
  short8 v;
  v[0] = (short)f2b(a.x * scale); v[1] = (short)f2b(a.y * scale);
  v[2] = (short)f2b(a.z * scale); v[3] = (short)f2b(a.w * scale);
  v[4] = (short)f2b(c.x * scale); v[5] = (short)f2b(c.y * scale);
  v[6] = (short)f2b(c.z * scale); v[7] = (short)f2b(c.w * scale);
  *(short8*)(wA + (size_t)fi * 512 + l * 8) = v;
  if (blockIdx.x == 0 && t < 320)
    ball[t] = (t < 32) ? bfv[t] * LOG2E : (t < 64) ? bgv[t - 32] : bhv[t - 64];
}

// Kernel 1: fused projection GEMM (bf16 MFMA) -> frag-ready fA/gB/hA.
__global__ __launch_bounds__(512) void k_fgh(
    const float* __restrict__ x, const unsigned short* __restrict__ wA,
    const float* __restrict__ ball,
    unsigned short* __restrict__ fA, unsigned short* __restrict__ gB,
    unsigned short* __restrict__ hA)
{
  __shared__ __align__(16) char smem[41984];       // max(xb 8KB, TL 41KB)
  unsigned short* xb = (unsigned short*)smem;      // [8 frag][64 l][8 e]
  unsigned short* TL = (unsigned short*)smem;      // [64 i][328 o] bf16
  const int bid = blockIdx.x;
  const int b = bid & 7, i0 = (bid >> 3) * 64;     // batch pinned to XCD
  const int t = threadIdx.x, w = t >> 6, l = t & 63;
  const int ig_w = w & 3, mg0 = (w >> 2) * 10;
  f32x4 acc[10] = {};
  for (int cc = 0; cc < 4; ++cc) {                 // c-chunks of 64
    __syncthreads();
    {  // stage x[cc*64..+64][i0..i0+64] as 8 B-frags (bf16)
      short8 v;
      const float* xp = x + ((size_t)b * CC + cc * 64 + w * 8) * NN + i0 + l;
      #pragma unroll
      for (int e = 0; e < 8; ++e) v[e] = (short)f2b(xp[(size_t)e * NN]);
      int frag = (w >> 2) * 4 + (l >> 4);
      int lp = (w & 3) * 16 + (l & 15);
      *(short8*)(xb + (frag * 64 + lp) * 8) = v;
    }
    __syncthreads();
    #pragma unroll
    for (int kg2 = 0; kg2 < 2; ++kg2) {
      short8 bfrag = *(const short8*)(xb + ((kg2 * 4 + ig_w) * 64 + l) * 8);
      int kg = cc * 2 + kg2;
      #pragma unroll
      for (int j = 0; j < 10; ++j) {
        short8 afrag = *(const short8*)(wA +
            ((size_t)((mg0 + j) * 8 + kg)) * 512 + l * 8);
        acc[j] = __builtin_amdgcn_mfma_f32_16x16x32_bf16(afrag, bfrag, acc[j], 0, 0, 0);
      }
    }
  }
  __syncthreads();
  // D-frags (+bias) -> transpose tile TL[i][o]
  #pragma unroll
  for (int j = 0; j < 10; ++j) {
    int ob = (mg0 + j) * 16 + (l >> 4) * 4;
    float4 bl = *(const float4*)(ball + ob);
    int irow = ig_w * 16 + (l & 15);
    ushort4 pv;
    pv.x = f2b(acc[j][0] + bl.x); pv.y = f2b(acc[j][1] + bl.y);
    pv.z = f2b(acc[j][2] + bl.z); pv.w = f2b(acc[j][3] + bl.w);
    *(ushort4*)(TL + irow * 328 + ob) = pv;
  }
  __syncthreads();
  // pack fA (o 0..31, already LOG2E-scaled) and gB (o 32..63)
  if (t < 256) {
    int kg_p = t >> 6;
    int o8 = (l >> 4) * 8;
    int irow = kg_p * 16 + (l & 15);
    short8 vf = *(const short8*)(TL + irow * 328 + o8);
    short8 vg = *(const short8*)(TL + irow * 328 + 32 + o8);
    size_t kgG = (size_t)b * 256 + (i0 >> 4) + kg_p;
    *(short8*)(fA + kgG * 512 + l * 8) = vf;
    *(short8*)(gB + kgG * 512 + l * 8) = vg;
  }
  // pack hA (o 64..319): 32 frags x 64 lanes over 512 threads
  #pragma unroll
  for (int q = 0; q < 4; ++q) {
    int slot = t + q * 512;
    int fr = slot >> 6, ll = slot & 63;
    int cg = fr >> 1, kcl = fr & 1;
    int orow = 64 + cg * 16 + (ll & 15);
    int pbase = kcl * 32 + (ll >> 4) * 8;
    short8 v;
    #pragma unroll
    for (int e = 0; e < 8; ++e) v[e] = (short)TL[(pbase + e) * 328 + orow];
    size_t idx = (((size_t)b * 16 + cg) * 128 + (i0 >> 5) + kcl) * 512 + ll * 8;
    *(short8*)(hA + idx) = v;
  }
}

// Kernel 2: fixed-shift softmax denom, LDS-staged g tiles shared by 8 waves.
// grid 256 (8 b x 32 kt of 128 k-rows); dbuf 2x16KB, one barrier/iter.
__global__ __launch_bounds__(512) void k_stats(
    const unsigned short* __restrict__ fA, const unsigned short* __restrict__ gB,
    float* __restrict__ cshift)
{
  __shared__ __align__(16) unsigned short sg[2][16 * 512];   // 2 x 16 KB
  const int bid = blockIdx.x;
  const int b = bid & 7, kt = bid >> 3;
  const int t = threadIdx.x, w = t >> 6, l = t & 63;
  const int li = l & 15, lh = l >> 4;
  short8 af = *(const short8*)(fA + ((size_t)b * 256 + kt * 8 + w) * 512 + l * 8);
  const unsigned short* gb = gB + (size_t)b * 256 * 512;
  f32x4 zero = {0.f, 0.f, 0.f, 0.f};
  // stage tile 0 (16 frags; each wave stages 2)
  {
    uint4 v0 = *(const uint4*)(gb + ((size_t)(w * 2 + 0) * 64 + l) * 8);
    uint4 v1 = *(const uint4*)(gb + ((size_t)(w * 2 + 1) * 64 + l) * 8);
    *(uint4*)(&sg[0][((w * 2 + 0) * 64 + l) * 8]) = v0;
    *(uint4*)(&sg[0][((w * 2 + 1) * 64 + l) * 8]) = v1;
  }
  __syncthreads();
  float s[4] = {0.f, 0.f, 0.f, 0.f};
  for (int jt = 0; jt < 16; ++jt) {
    if (jt < 15) {   // stage next tile into the other buffer
      uint4 v0 = *(const uint4*)(gb + ((size_t)((jt + 1) * 16 + w * 2 + 0) * 64 + l) * 8);
      uint4 v1 = *(const uint4*)(gb + ((size_t)((jt + 1) * 16 + w * 2 + 1) * 64 + l) * 8);
      unsigned short* dst = &sg[(jt + 1) & 1][0];
      *(uint4*)(dst + ((w * 2 + 0) * 64 + l) * 8) = v0;
      *(uint4*)(dst + ((w * 2 + 1) * 64 + l) * 8) = v1;
    }
    const unsigned short* src = &sg[jt & 1][0];
    #pragma unroll
    for (int jf = 0; jf < 16; ++jf) {
      short8 bfrag = *(const short8*)(src + (jf * 64 + l) * 8);
      f32x4 d = __builtin_amdgcn_mfma_f32_16x16x32_bf16(af, bfrag, zero, 0, 0, 0);
      s[0] += exp2f(d[0] - SHIFT);
      s[1] += exp2f(d[1] - SHIFT);
      s[2] += exp2f(d[2] - SHIFT);
      s[3] += exp2f(d[3] - SHIFT);
    }
    __syncthreads();
  }
  #pragma unroll
  for (int mk = 1; mk < 16; mk <<= 1)
    #pragma unroll
    for (int r = 0; r < 4; ++r) s[r] += __shfl_xor(s[r], mk);
  if (li == 0) {
    #pragma unroll
    for (int r = 0; r < 4; ++r) {
      size_t idx = (size_t)b * NN + (kt * 8 + w) * 16 + lh * 4 + r;
      cshift[idx] = SHIFT + log2f(fmaxf(s[r], 1e-30f));
    }
  }
}

// Kernel 3: out[c][i] via D[i][c] = P^T . h^T. 8 waves, chunk = 128 k.
// PIPELINED: iteration ch = {issue hf(ch) loads; produce P(ch+1) into
// buf[(ch+1)&1] (S-MFMA + exp2 + scatter, VALU overlaps PV MFMAs);
// PV(ch) from buf[ch&1]; one barrier}. setprio(1) around the PV cluster.
__global__ __launch_bounds__(512, 4) void k_out(
    const unsigned short* __restrict__ fA, const unsigned short* __restrict__ gB,
    const unsigned short* __restrict__ hA,
    const float* __restrict__ csv,
    const float* __restrict__ x, const float* __restrict__ gamma,
    float* __restrict__ out)
{
  __shared__ __align__(16) unsigned short pbuf[2 * 16 * 512];   // 2 x 16 KB
  const int bid = blockIdx.x;
  const int b = bid & 7, i0 = (bid >> 3) * 64;     // batch pinned to XCD
  const int t = threadIdx.x, w = t >> 6, l = t & 63;
  const int li = l & 15, lh = l >> 4;
  const unsigned short* fAb = fA + ((size_t)b * 256 + w) * 512 + l * 8;
  const unsigned short* hAb = hA + ((size_t)b * 16 + w * 2) * (size_t)128 * 512 + l * 8;
  const float* cs = csv + (size_t)b * NN + w * 16 + lh * 4;
  // persistent g B-frags for this block's 4 ig columns
  short8 g[4];
  #pragma unroll
  for (int ig = 0; ig < 4; ++ig)
    g[ig] = *(const short8*)(gB + ((size_t)b * 256 + (i0 >> 4) + ig) * 512 + l * 8);
  // scatter slot (verified r4-r6): wave w's S rows -> B-frag lane/word
  const int pl = ((w & 1) * 2 + (lh >> 1)) * 16 + li;
  const int pwo = pl * 8 + (lh & 1) * 4;
  f32x4 zero = {0.f, 0.f, 0.f, 0.f};
  f32x4 acc[2][4] = {};
  // ---- prologue: produce P(0) into buf0; prefetch af/cc for chunk 1
  short8 afc = *(const short8*)(fAb);
  float4 ccc = *(const float4*)(cs);
  #pragma unroll
  for (int ig = 0; ig < 4; ++ig) {
    f32x4 sfr = __builtin_amdgcn_mfma_f32_16x16x32_bf16(afc, g[ig], zero, 0, 0, 0);
    uint2 v;
    v.x = pk2(exp2f(sfr[0] - ccc.x), exp2f(sfr[1] - ccc.y));
    v.y = pk2(exp2f(sfr[2] - ccc.z), exp2f(sfr[3] - ccc.w));
    *(uint2*)(pbuf + ((size_t)((w >> 1) * 4 + ig)) * 512 + pwo) = v;
  }
  afc = *(const short8*)(fAb + (size_t)8 * 512);
  ccc = *(const float4*)(cs + 128);
  __syncthreads();
  for (int ch = 0; ch < 32; ++ch) {
    unsigned short* pb  = pbuf + (ch & 1) * (16 * 512);
    unsigned short* pnx = pbuf + ((ch + 1) & 1) * (16 * 512);
    // issue h B-frag loads for PV(ch) — latency hides under S-production
    short8 hf[8];
    #pragma unroll
    for (int cg = 0; cg < 2; ++cg)
      #pragma unroll
      for (int kb = 0; kb < 4; ++kb)
        hf[cg * 4 + kb] = *(const short8*)(hAb +
            ((size_t)cg * 128 + ch * 4 + kb) * 512);
    // produce P(ch+1): VALU work overlaps PV MFMA pipe
    if (ch < 31) {
      #pragma unroll
      for (int ig = 0; ig < 4; ++ig) {
        f32x4 sfr = __builtin_amdgcn_mfma_f32_16x16x32_bf16(afc, g[ig], zero, 0, 0, 0);
        uint2 v;
        v.x = pk2(exp2f(sfr[0] - ccc.x), exp2f(sfr[1] - ccc.y));
        v.y = pk2(exp2f(sfr[2] - ccc.z), exp2f(sfr[3] - ccc.w));
        *(uint2*)(pnx + ((size_t)((w >> 1) * 4 + ig)) * 512 + pwo) = v;
      }
      const int ch2 = (ch < 30) ? (ch + 2) : 31;
      afc = *(const short8*)(fAb + (size_t)ch2 * 8 * 512);
      ccc = *(const float4*)(cs + ch2 * 128);
    }
    // PV(ch): 32 MFMA from LDS P + prefetched h
    __builtin_amdgcn_s_setprio(1);
    #pragma unroll
    for (int kb = 0; kb < 4; ++kb)
      #pragma unroll
      for (int ig = 0; ig < 4; ++ig) {
        short8 pf = *(const short8*)(pb + ((kb * 4 + ig) * 64 + l) * 8);
        acc[0][ig] = __builtin_amdgcn_mfma_f32_16x16x32_bf16(pf, hf[kb], acc[0][ig], 0, 0, 0);
        acc[1][ig] = __builtin_amdgcn_mfma_f32_16x16x32_bf16(pf, hf[4 + kb], acc[1][ig], 0, 0, 0);
      }
    __builtin_amdgcn_s_setprio(0);
    __syncthreads();
  }
  // epilogue: D[m=i][n=c] -> lane holds 4 consecutive i at fixed c
  const float gm = gamma[0];
  #pragma unroll
  for (int cg = 0; cg < 2; ++cg)
    #pragma unroll
    for (int ig = 0; ig < 4; ++ig) {
      int c = w * 32 + cg * 16 + li;
      int i = i0 + ig * 16 + lh * 4;
      size_t off = ((size_t)b * CC + c) * NN + i;
      float4 xv = *(const float4*)(x + off);
      float4 ov;
      ov.x = gm * acc[cg][ig][0] + xv.x;
      ov.y = gm * acc[cg][ig][1] + xv.y;
      ov.z = gm * acc[cg][ig][2] + xv.z;
      ov.w = gm * acc[cg][ig][3] + xv.w;
      *(float4*)(out + off) = ov;
    }
}

extern "C" void kernel_launch(void* const* d_in, const int* in_sizes, int n_in,
                              void* d_out, int out_size, void* d_ws, size_t ws_size,
                              hipStream_t stream)
{
  const float* x     = (const float*)d_in[0];
  const float* Wf    = (const float*)d_in[1];
  const float* bf    = (const float*)d_in[2];
  const float* Wg    = (const float*)d_in[3];
  const float* bg    = (const float*)d_in[4];
  const float* Wh    = (const float*)d_in[5];
  const float* bh    = (const float*)d_in[6];
  const float* gamma = (const float*)d_in[7];
  float* out = (float*)d_out;

  char* wsb = (char*)d_ws;
  float* cshift = (float*)(wsb + 131072);
  unsigned short* wA = (unsigned short*)(wsb + 262144);
  float* ball        = (float*)(wsb + 425984);
  unsigned short* fA = (unsigned short*)(wsb + 427520);
  unsigned short* gB = (unsigned short*)(wsb + 2524672);
  unsigned short* hA = (unsigned short*)(wsb + 4621824);

  k_wprep<<<40,  256, 0, stream>>>(Wf, bf, Wg, bg, Wh, bh, wA, ball);
  k_fgh  <<<512, 512, 0, stream>>>(x, wA, ball, fA, gB, hA);
  k_stats<<<256, 512, 0, stream>>>(fA, gB, cshift);
  k_out  <<<512, 512, 0, stream>>>(fA, gB, hA, cshift, x, gamma, out);
}